// Round 9
// baseline (247.189 us; speedup 1.0000x reference)
//
#include <hip/hip_runtime.h>
#include <stdint.h>

#define N_ROWS 4096
#define DIM    1024
#define NCLS   64
#define EPSV   0.1f
#define GRID   528

typedef __attribute__((ext_vector_type(4))) float f32x4;

__device__ __forceinline__ void async_cp16(const void* g, void* l) {
    __builtin_amdgcn_global_load_lds((const __attribute__((address_space(1))) void*)g,
                                     (__attribute__((address_space(3))) void*)l,
                                     16, 0, 0);
}

__device__ __forceinline__ float softplus(float x) {
    return fmaxf(x, 0.f) + __logf(1.f + __expf(-fabsf(x)));
}

// grid barrier: monotonic counter (zeroed by hipMemsetAsync each call).
// All blocks co-resident (528 <= 3 blocks/CU x 256 CU), so spin is safe.
__device__ __forceinline__ void gbar(unsigned int* cnt, unsigned int target) {
    __syncthreads();                       // also drains each wave's vmcnt
    if (threadIdx.x == 0) {
        __threadfence();                   // release: prior writes visible
        atomicAdd(cnt, 1u);
        while (__hip_atomic_load(cnt, __ATOMIC_RELAXED, __HIP_MEMORY_SCOPE_AGENT) < target)
            __builtin_amdgcn_s_sleep(8);
        __threadfence();                   // acquire
    }
    __syncthreads();
}

__global__ __launch_bounds__(256, 3) void k_fused(
        const float* __restrict__ X, const int* __restrict__ tgt,
        float* __restrict__ w, float* __restrict__ scal,
        float* __restrict__ sq,
        unsigned int* __restrict__ Xb8, unsigned int* __restrict__ XWb8,
        float* __restrict__ csumR, float* __restrict__ csqR,
        unsigned int* __restrict__ syncc, float* __restrict__ out) {
    __shared__ __align__(16) unsigned char As[4][4096];
    __shared__ __align__(16) unsigned char Bs[4][4096];
    __shared__ float sqI[128], sqJ[128];
    __shared__ int   tIs[128], tJs[128];
    __shared__ float red[4];
    __shared__ int   hist[NCLS];
    __shared__ int   nrows_s;

    int tid = threadIdx.x, blk = blockIdx.x;
    int wave = tid >> 6, lane = tid & 63;

    // ================= Phase A: per-class sum/sqsum (blocks 0..255) ==========
    if (blk < 256) {
        int* rows = (int*)&As[0][0];                 // 16KB alias, phase-local
        int c = blk >> 2, q = blk & 3;
        if (tid == 0) nrows_s = 0;
        __syncthreads();
        for (int i = tid; i < N_ROWS; i += 256)
            if (tgt[i] == c) { int p = atomicAdd(&nrows_s, 1); rows[p] = i; }
        __syncthreads();
        int n = nrows_s;
        int d = q * 256 + tid;
        float s = 0.f, qq = 0.f;
        #pragma unroll 4
        for (int r = 0; r < n; r++) {
            float x = X[(size_t)rows[r] * DIM + d];
            s += x; qq += x * x;
        }
        csumR[c * DIM + d] = s;
        csqR [c * DIM + d] = qq;
    }
    gbar(syncc, GRID);

    // ================= Phase B: weights + fp8 scale (blocks 0..3) ============
    if (blk < 4) {
        if (tid < NCLS) hist[tid] = 0;
        __syncthreads();
        for (int i = tid; i < N_ROWS; i += 256) atomicAdd(&hist[tgt[i]], 1);
        __syncthreads();
        long long sp = 0, ss = 0;
        for (int c = 0; c < NCLS; c++) { long long cc = hist[c]; sp += cc * (cc - 1); ss += cc * cc; }
        float cnt_pos = (float)sp;
        float cnt_neg = (float)((long long)N_ROWS * N_ROWS - ss);
        int d = blk * 256 + tid;
        float A = 0.f, X2 = 0.f, T = 0.f, SS = 0.f;
        #pragma unroll 8
        for (int c = 0; c < NCLS; c++) {
            float s = csumR[c * DIM + d];
            float q = csqR [c * DIM + d];
            A += (float)hist[c] * q; X2 += q; T += s; SS += s * s;
        }
        float posnum = 2.f * (A - SS);
        float negnum = 2.f * ((float)N_ROWS * X2 - A - T * T + SS);
        float wd = cnt_neg / (negnum + EPSV) - cnt_pos / (posnum + EPSV);
        w[d] = wd;
        if (blk == 0) {
            float m = wd * wd;
            for (int off = 32; off; off >>= 1) m += __shfl_down(m, off, 64);
            if ((tid & 63) == 0) red[wave] = m;
            __syncthreads();
            if (tid == 0) {
                float ms = (red[0] + red[1] + red[2] + red[3]) / 256.f;
                scal[0] = exp2f(roundf(log2f(sqrtf(ms) + 1e-30f)));
                out[0] = 0.0f;
            }
        }
    }
    gbar(syncc, 2 * GRID);

    // ================= Phase C: xw, sq, fp8 casts (baked bank swizzle) =======
    // uniform 8 iterations so in-loop __syncthreads stays wave-uniform
    {
        float inv_sw = 1.0f / scal[0];
        #pragma unroll 1
        for (int i = 0; i < 8; i++) {
            int row = blk + i * GRID;
            bool act = row < N_ROWS;
            float4 x = act ? ((const float4*)(X + (size_t)row * DIM))[tid]
                           : make_float4(0.f, 0.f, 0.f, 0.f);
            float4 ww = ((const float4*)w)[tid];
            float4 xw = make_float4(x.x * ww.x, x.y * ww.y, x.z * ww.z, x.w * ww.w);
            float p = x.x * xw.x + x.y * xw.y + x.z * xw.z + x.w * xw.w;
            unsigned ux = __builtin_amdgcn_cvt_pk_fp8_f32(x.x, x.y, 0, false);
            ux = __builtin_amdgcn_cvt_pk_fp8_f32(x.z, x.w, ux, true);
            unsigned uw = __builtin_amdgcn_cvt_pk_fp8_f32(xw.x * inv_sw, xw.y * inv_sw, 0, false);
            uw = __builtin_amdgcn_cvt_pk_fp8_f32(xw.z * inv_sw, xw.w * inv_sw, uw, true);
            // logical: k-step t=tid>>3, quad q=(tid>>1)&3, half o=tid&1;
            // physical quad = q ^ ((row>>2)&3)  (bank swizzle baked in HBM)
            int t = tid >> 3, q = (tid >> 1) & 3, o = tid & 1;
            int ssw = (row >> 2) & 3;
            int widx = row * 256 + t * 8 + (q ^ ssw) * 2 + o;
            if (act) { Xb8[widx] = ux; XWb8[widx] = uw; }
            for (int off = 32; off; off >>= 1) p += __shfl_down(p, off, 64);
            if ((tid & 63) == 0) red[wave] = p;
            __syncthreads();
            if (act && tid == 0) sq[row] = red[0] + red[1] + red[2] + red[3];
            __syncthreads();
        }
    }
    gbar(syncc, 3 * GRID);

    // ================= Phase D: fp8 MFMA gram + softplus + masked mean =======
    // balanced triangular decode: group g owns jt in {g,15-g,16+g,31-g}
    int g = blk & 7, s = blk >> 3;
    int j0 = g, j1 = 15 - g, j2 = 16 + g;
    int n0 = j0 + 1, n1 = j1 + 1, n2 = j2 + 1;
    int jt, it;
    if      (s < n0)           { jt = j0; it = s; }
    else if (s < n0 + n1)      { jt = j1; it = s - n0; }
    else if (s < n0 + n1 + n2) { jt = j2; it = s - n0 - n1; }
    else                       { jt = 31 - g; it = s - n0 - n1 - n2; }

    const unsigned char* Xc  = (const unsigned char*)Xb8;
    const unsigned char* XWc = (const unsigned char*)XWb8;
    bool isA = wave < 2;
    const unsigned char* srcb = (isA ? Xc : XWc) + (size_t)((isA ? it : jt) * 128) * DIM;
    unsigned char* slab = isA ? &As[0][0] : &Bs[0][0];
    const unsigned char* gp[2];
    unsigned char* lb[2];
    #pragma unroll
    for (int si = 0; si < 2; si++) {
        int ch = (wave & 1) * 128 + si * 64 + lane;
        int r = ch >> 1, h = ch & 1;
        gp[si] = srcb + (size_t)r * DIM + h * 16;
        lb[si] = slab + ((wave & 1) * 128 + si * 64) * 16;   // wave-uniform base
    }

    int lr = lane & 15, kq = lane >> 4;
    int offA[4], offB[4];
    int wrow = (wave >> 1) * 64, wcol = (wave & 1) * 64;
    #pragma unroll
    for (int mi = 0; mi < 4; mi++) {
        int row = wrow + mi * 16 + lr;
        offA[mi] = row * 32 + (kq ^ ((row >> 2) & 3)) * 8;
        int col = wcol + mi * 16 + lr;
        offB[mi] = col * 32 + (kq ^ ((col >> 2) & 3)) * 8;
    }

    f32x4 acc[4][4];
    #pragma unroll
    for (int i = 0; i < 4; i++)
        #pragma unroll
        for (int j = 0; j < 4; j++) acc[i][j] = (f32x4){0.f, 0.f, 0.f, 0.f};

    #pragma unroll
    for (int st = 0; st < 3; st++)
        #pragma unroll
        for (int si = 0; si < 2; si++)
            async_cp16(gp[si] + st * 32, lb[si] + st * 4096);

    for (int kk = 0; kk < 32; kk++) {
        if      (kk < 30)  asm volatile("s_waitcnt vmcnt(4)" ::: "memory");
        else if (kk == 30) asm volatile("s_waitcnt vmcnt(2)" ::: "memory");
        else               asm volatile("s_waitcnt vmcnt(0)" ::: "memory");
        asm volatile("s_barrier" ::: "memory");
        if (kk < 29) {
            #pragma unroll
            for (int si = 0; si < 2; si++)
                async_cp16(gp[si] + (kk + 3) * 32, lb[si] + ((kk + 3) & 3) * 4096);
        }
        int rd = kk & 3;
        const unsigned char* Ab = As[rd];
        const unsigned char* Bb = Bs[rd];
        long long av[4], bv[4];
        #pragma unroll
        for (int i = 0; i < 4; i++) {
            av[i] = *(const long long*)(Ab + offA[i]);
            bv[i] = *(const long long*)(Bb + offB[i]);
        }
        #pragma unroll
        for (int i = 0; i < 4; i++)
            #pragma unroll
            for (int j = 0; j < 4; j++)
                acc[i][j] = __builtin_amdgcn_mfma_f32_16x16x32_fp8_fp8(av[i], bv[j], acc[i][j], 0, 0, 0);
    }

    __syncthreads();
    if (tid < 128) { sqI[tid] = sq[it * 128 + tid]; tIs[tid] = tgt[it * 128 + tid]; }
    else { int u = tid - 128; sqJ[u] = sq[jt * 128 + u]; tJs[u] = tgt[jt * 128 + u]; }
    __syncthreads();

    float sw2 = 2.0f * scal[0];
    float sum = 0.f;
    bool diagTile = (it == jt);
    #pragma unroll
    for (int j = 0; j < 4; j++) {
        int col = wcol + j * 16 + (lane & 15);            // C/D: col = lane&15
        float sj = sqJ[col]; int tj = tJs[col];
        #pragma unroll
        for (int i = 0; i < 4; i++) {
            int rbase = wrow + i * 16 + (lane >> 4) * 4;  // C/D: row = quad*4+reg
            #pragma unroll
            for (int r = 0; r < 4; r++) {
                int rowp = rbase + r;
                float S = sqI[rowp] + sj - sw2 * acc[i][j][r];
                float v;
                if (tIs[rowp] == tj) v = (diagTile && rowp == col) ? 0.f : softplus(-S);
                else                 v = softplus(S);
                sum += v;
            }
        }
    }
    float scale = (diagTile ? 1.f : 2.f) * (1.f / ((float)N_ROWS * (float)(N_ROWS - 1)));
    sum *= scale;
    for (int off = 32; off; off >>= 1) sum += __shfl_down(sum, off, 64);
    if (lane == 0) red[wave] = sum;
    __syncthreads();
    if (tid == 0) atomicAdd(out, red[0] + red[1] + red[2] + red[3]);
}

extern "C" void kernel_launch(void* const* d_in, const int* in_sizes, int n_in,
                              void* d_out, int out_size, void* d_ws, size_t ws_size,
                              hipStream_t stream) {
    const float* X  = (const float*)d_in[0];
    const int* tgt  = (const int*)d_in[1];
    float* out = (float*)d_out;
    char* ws = (char*)d_ws;
    const size_t MB = 1u << 20;

    float* w      = (float*)ws;                           // 4 KB
    float* sq     = (float*)(ws + 4096);                  // 16 KB
    float* scal   = (float*)(ws + 24576);                 // 4 B
    unsigned int* syncc = (unsigned int*)(ws + 32768);    // 64 B
    unsigned int* Xb8   = (unsigned int*)(ws + 1 * MB);   // 4 MB
    unsigned int* XWb8  = (unsigned int*)(ws + 5 * MB);   // 4 MB
    float* csumR  = (float*)(ws + 9 * MB);                // 256 KB
    float* csqR   = (float*)(ws + 9 * MB + 256 * 1024);   // 256 KB

    hipMemsetAsync(syncc, 0, 64, stream);
    k_fused<<<GRID, 256, 0, stream>>>(X, tgt, w, scal, sq, Xb8, XWb8,
                                      csumR, csqR, syncc, out);
}

// Round 10
// 120.931 us; speedup vs baseline: 2.0441x; 2.0441x over previous
//
#include <hip/hip_runtime.h>
#include <stdint.h>

#define N_ROWS 4096
#define DIM    1024
#define NCLS   64
#define EPSV   0.1f

typedef __attribute__((ext_vector_type(4))) float f32x4;

__device__ __forceinline__ void async_cp16(const void* g, void* l) {
    __builtin_amdgcn_global_load_lds((const __attribute__((address_space(1))) void*)g,
                                     (__attribute__((address_space(3))) void*)l,
                                     16, 0, 0);
}

__device__ __forceinline__ float softplus(float x) {
    return fmaxf(x, 0.f) + __logf(1.f + __expf(-fabsf(x)));
}

// ---------------- K1: per-class sum/sqsum via row gather ---------------------
__global__ __launch_bounds__(256) void k_cstats(const float* __restrict__ X,
                                                const int* __restrict__ tgt,
                                                float* __restrict__ csumR,
                                                float* __restrict__ csqR) {
    __shared__ int rows[N_ROWS];
    __shared__ int nrows_s;
    int tid = threadIdx.x;
    int c = blockIdx.x >> 2, q = blockIdx.x & 3;
    if (tid == 0) nrows_s = 0;
    __syncthreads();
    for (int i = tid; i < N_ROWS; i += 256)
        if (tgt[i] == c) { int p = atomicAdd(&nrows_s, 1); rows[p] = i; }
    __syncthreads();
    int n = nrows_s;
    int d = q * 256 + tid;
    float s = 0.f, qq = 0.f;
    #pragma unroll 4
    for (int r = 0; r < n; r++) {
        float x = X[(size_t)rows[r] * DIM + d];
        s += x; qq += x * x;
    }
    csumR[c * DIM + d] = s;
    csqR [c * DIM + d] = qq;
}

// ---------------- K2: counts + weights + fp8 scale + zero loss ---------------
__global__ __launch_bounds__(128) void k_weights(const int* __restrict__ tgt,
                                                 const float* __restrict__ csumR,
                                                 const float* __restrict__ csqR,
                                                 float* __restrict__ w,
                                                 float* __restrict__ scal,
                                                 float* __restrict__ loss_out) {
    __shared__ int hist[NCLS];
    __shared__ float redw[2];
    int tid = threadIdx.x, b = blockIdx.x;
    if (tid < NCLS) hist[tid] = 0;
    __syncthreads();
    for (int i = tid; i < N_ROWS; i += 128) atomicAdd(&hist[tgt[i]], 1);
    __syncthreads();
    long long sp = 0, ss = 0;
    for (int c = 0; c < NCLS; c++) { long long cc = hist[c]; sp += cc * (cc - 1); ss += cc * cc; }
    float cnt_pos = (float)sp;
    float cnt_neg = (float)((long long)N_ROWS * N_ROWS - ss);
    int d = b * 128 + tid;
    float A = 0.f, X2 = 0.f, T = 0.f, SS = 0.f;
    #pragma unroll 8
    for (int c = 0; c < NCLS; c++) {
        float s = csumR[c * DIM + d];
        float q = csqR [c * DIM + d];
        A += (float)hist[c] * q; X2 += q; T += s; SS += s * s;
    }
    float posnum = 2.f * (A - SS);
    float negnum = 2.f * ((float)N_ROWS * X2 - A - T * T + SS);
    float wd = cnt_neg / (negnum + EPSV) - cnt_pos / (posnum + EPSV);
    w[d] = wd;
    float m = wd * wd;
    for (int off = 32; off; off >>= 1) m += __shfl_down(m, off, 64);
    int wv = tid >> 6, ln = tid & 63;
    if (ln == 0) redw[wv] = m;
    __syncthreads();
    if (b == 0 && tid == 0) {
        float ms = (redw[0] + redw[1]) / 128.f;
        scal[0] = exp2f(roundf(log2f(sqrtf(ms) + 1e-30f)));
        loss_out[0] = 0.0f;
    }
}

// ---------------- K3: xw, sq (fp32 exact), fp8 casts with baked swizzle ------
// Global fp8 layout: within each row and each 32B k-step, logical 8B quad q
// is stored at physical quad q ^ ((row>>2)&3) -> the gemm's contiguous 16B
// staging yields conflict-free ds_read_b64 fragment reads (verified: a
// 16-lane phase covers all 32 banks exactly once).
__global__ __launch_bounds__(256) void k_prep(const float* __restrict__ X,
                                              const float* __restrict__ w,
                                              const float* __restrict__ scal,
                                              unsigned int* __restrict__ Xb8,
                                              unsigned int* __restrict__ XWb8,
                                              float* __restrict__ sq) {
    int row = blockIdx.x, tid = threadIdx.x;
    float inv_sw = 1.0f / scal[0];
    float4 x  = ((const float4*)(X + (size_t)row * DIM))[tid];
    float4 ww = ((const float4*)w)[tid];
    float4 xw = make_float4(x.x * ww.x, x.y * ww.y, x.z * ww.z, x.w * ww.w);
    float p = x.x * xw.x + x.y * xw.y + x.z * xw.z + x.w * xw.w;
    unsigned ux = __builtin_amdgcn_cvt_pk_fp8_f32(x.x, x.y, 0, false);
    ux = __builtin_amdgcn_cvt_pk_fp8_f32(x.z, x.w, ux, true);
    unsigned uw = __builtin_amdgcn_cvt_pk_fp8_f32(xw.x * inv_sw, xw.y * inv_sw, 0, false);
    uw = __builtin_amdgcn_cvt_pk_fp8_f32(xw.z * inv_sw, xw.w * inv_sw, uw, true);
    int t = tid >> 3, q = (tid >> 1) & 3, o = tid & 1;
    int s = (row >> 2) & 3;
    int widx = row * 256 + t * 8 + (q ^ s) * 2 + o;
    Xb8 [widx] = ux;
    XWb8[widx] = uw;
    for (int off = 32; off; off >>= 1) p += __shfl_down(p, off, 64);
    __shared__ float red[4];
    int wv = tid >> 6, ln = tid & 63;
    if (ln == 0) red[wv] = p;
    __syncthreads();
    if (tid == 0) sq[row] = red[0] + red[1] + red[2] + red[3];
}

// ---------------- K4: fused fp8 MFMA gram + softplus + masked mean -----------
// 128x128 tiles, balanced groups (g owns jt in {g,15-g,16+g,31-g}; 528 blocks).
// 512 thr = 8 waves (2x4), wave = 64x32 (4x2 frags -> acc = 32 AGPRs).
// __launch_bounds__(512,4): cap unified regs at 128 -> 4 waves/SIMD ->
// 16 waves/CU (2 blocks/CU), double the latency-hiding TLP of prior rounds.
// Baked-global bank swizzle: staging is contiguous; fragment reads conflict-
// free. Depth-3 pipeline: 4 LDS buffer pairs, 1 staging load/thread/step,
// raw s_barrier + manual vmcnt.
__global__ __launch_bounds__(512, 4) void k_gemm_loss(const unsigned char* __restrict__ Xb8,
                                                      const unsigned char* __restrict__ XWb8,
                                                      const float* __restrict__ sq,
                                                      const int* __restrict__ tgt,
                                                      const float* __restrict__ scal,
                                                      float* __restrict__ loss) {
    __shared__ __align__(16) unsigned char As[4][4096];
    __shared__ __align__(16) unsigned char Bs[4][4096];
    __shared__ float sqI[128], sqJ[128];
    __shared__ int   tIs[128], tJs[128];
    __shared__ float red[8];

    int tid = threadIdx.x;
    int wave = tid >> 6, lane = tid & 63;

    // balanced triangular decode
    int g = blockIdx.x & 7, s = blockIdx.x >> 3;
    int j0 = g, j1 = 15 - g, j2 = 16 + g;
    int n0 = j0 + 1, n1 = j1 + 1, n2 = j2 + 1;
    int jt, it;
    if      (s < n0)           { jt = j0; it = s; }
    else if (s < n0 + n1)      { jt = j1; it = s - n0; }
    else if (s < n0 + n1 + n2) { jt = j2; it = s - n0 - n1; }
    else                       { jt = 31 - g; it = s - n0 - n1 - n2; }

    // staging: waves 0-3 -> A slab, waves 4-7 -> B slab; 1 contiguous 16B
    // chunk per thread per step. chunk ch = (wave&3)*64 + lane -> row r =
    // ch>>1, half h = ch&1 (global layout already bank-swizzled).
    bool isA = wave < 4;
    const unsigned char* srcb = (isA ? Xb8 : XWb8) + (size_t)((isA ? it : jt) * 128) * DIM;
    unsigned char* slab = isA ? &As[0][0] : &Bs[0][0];
    int ch = (wave & 3) * 64 + lane;
    int r = ch >> 1, h = ch & 1;
    const unsigned char* gp = srcb + (size_t)r * DIM + h * 16;
    unsigned char* lb = slab + (wave & 3) * 1024;        // wave-uniform base

    // fragment LDS offsets: physical quad = kq ^ ((row>>2)&3)
    int lr = lane & 15, kq = lane >> 4;
    int offA[4], offB[2];
    int wrow = (wave >> 2) * 64, wcol = (wave & 3) * 32;
    #pragma unroll
    for (int mi = 0; mi < 4; mi++) {
        int row = wrow + mi * 16 + lr;
        offA[mi] = row * 32 + (kq ^ ((row >> 2) & 3)) * 8;
    }
    #pragma unroll
    for (int nj = 0; nj < 2; nj++) {
        int col = wcol + nj * 16 + lr;
        offB[nj] = col * 32 + (kq ^ ((col >> 2) & 3)) * 8;
    }

    f32x4 acc[4][2];
    #pragma unroll
    for (int i = 0; i < 4; i++)
        #pragma unroll
        for (int j = 0; j < 2; j++) acc[i][j] = (f32x4){0.f, 0.f, 0.f, 0.f};

    // prologue: stage K-steps 0,1,2 into buffers 0,1,2 (3 loads in flight)
    #pragma unroll
    for (int st = 0; st < 3; st++) async_cp16(gp + st * 32, lb + st * 4096);

    for (int kk = 0; kk < 32; kk++) {
        if      (kk < 30)  asm volatile("s_waitcnt vmcnt(2)" ::: "memory");
        else if (kk == 30) asm volatile("s_waitcnt vmcnt(1)" ::: "memory");
        else               asm volatile("s_waitcnt vmcnt(0)" ::: "memory");
        asm volatile("s_barrier" ::: "memory");
        if (kk < 29)                        // prefetch kk+3 into buffer (kk+3)&3
            async_cp16(gp + (kk + 3) * 32, lb + ((kk + 3) & 3) * 4096);
        int rd = kk & 3;
        const unsigned char* Ab = As[rd];
        const unsigned char* Bb = Bs[rd];
        long long av[4], bv[2];
        #pragma unroll
        for (int i = 0; i < 4; i++) av[i] = *(const long long*)(Ab + offA[i]);
        #pragma unroll
        for (int j = 0; j < 2; j++) bv[j] = *(const long long*)(Bb + offB[j]);
        #pragma unroll
        for (int i = 0; i < 4; i++)
            #pragma unroll
            for (int j = 0; j < 2; j++)
                acc[i][j] = __builtin_amdgcn_mfma_f32_16x16x32_fp8_fp8(av[i], bv[j], acc[i][j], 0, 0, 0);
    }

    // epilogue: S = sq_i + sq_j - 2*sw*G', masked softplus, x2 off-diagonal
    __syncthreads();
    if (tid < 128)      { sqI[tid] = sq[it * 128 + tid]; tIs[tid] = tgt[it * 128 + tid]; }
    else if (tid < 256) { int u = tid - 128; sqJ[u] = sq[jt * 128 + u]; tJs[u] = tgt[jt * 128 + u]; }
    __syncthreads();

    float sw2 = 2.0f * scal[0];
    float sum = 0.f;
    bool diagTile = (it == jt);
    #pragma unroll
    for (int j = 0; j < 2; j++) {
        int col = wcol + j * 16 + (lane & 15);            // C/D: col = lane&15
        float sj = sqJ[col]; int tj = tJs[col];
        #pragma unroll
        for (int i = 0; i < 4; i++) {
            int rbase = wrow + i * 16 + (lane >> 4) * 4;  // C/D: row = quad*4+reg
            #pragma unroll
            for (int rr = 0; rr < 4; rr++) {
                int rowp = rbase + rr;
                float S = sqI[rowp] + sj - sw2 * acc[i][j][rr];
                float v;
                if (tIs[rowp] == tj) v = (diagTile && rowp == col) ? 0.f : softplus(-S);
                else                 v = softplus(S);
                sum += v;
            }
        }
    }
    float scale = (diagTile ? 1.f : 2.f) * (1.f / ((float)N_ROWS * (float)(N_ROWS - 1)));
    sum *= scale;
    for (int off = 32; off; off >>= 1) sum += __shfl_down(sum, off, 64);
    if (lane == 0) red[wave] = sum;
    __syncthreads();
    if (tid == 0) {
        float t = 0.f;
        #pragma unroll
        for (int wv = 0; wv < 8; wv++) t += red[wv];
        atomicAdd(loss, t);
    }
}

extern "C" void kernel_launch(void* const* d_in, const int* in_sizes, int n_in,
                              void* d_out, int out_size, void* d_ws, size_t ws_size,
                              hipStream_t stream) {
    const float* X  = (const float*)d_in[0];
    const int* tgt  = (const int*)d_in[1];
    float* out = (float*)d_out;
    char* ws = (char*)d_ws;
    const size_t MB = 1u << 20;

    float* w      = (float*)ws;                         // 4 KB
    float* sq     = (float*)(ws + 4096);                // 16 KB
    float* scal   = (float*)(ws + 24576);               // 4 B
    unsigned int* Xb8  = (unsigned int*)(ws + 1 * MB);  // 4 MB
    unsigned int* XWb8 = (unsigned int*)(ws + 5 * MB);  // 4 MB
    float* csumR  = (float*)(ws + 9 * MB);              // 256 KB
    float* csqR   = (float*)(ws + 9 * MB + 256 * 1024); // 256 KB

    k_cstats  <<<256,  256, 0, stream>>>(X, tgt, csumR, csqR);
    k_weights <<<8,    128, 0, stream>>>(tgt, csumR, csqR, w, scal, out);
    k_prep    <<<4096, 256, 0, stream>>>(X, w, scal, Xb8, XWb8, sq);
    k_gemm_loss<<<528, 512, 0, stream>>>((const unsigned char*)Xb8, (const unsigned char*)XWb8,
                                         sq, tgt, scal, out);
}